// Round 1
// 1771.027 us; speedup vs baseline: 1.2902x; 1.2902x over previous
//
#include <hip/hip_runtime.h>

// ---------------------------------------------------------------------------
// SwinTimeBlock: B=8,T=8,H=W=56,C=192,WS=7,NH=6,d=32,L=3136,HID=768
// tokens = 200704. All GEMMs bf16-MFMA (16x16x32), fp32 accumulate.
// R1 changes: BM=128/BK=64 GEMM with global_load_lds + XOR-swizzled LDS,
//             LN2 fused into proj epilogue (ln_rows kernels removed).
// Memory plan:
//   ws:    [weights_bf16 (1.7MB) | bufA 77.07MB (xn) | bufB 231.2MB (qkv)]
//          bufA+bufB contiguous = 308.28MB = h (200704x768 bf16) for MLP.
//   d_out: sections out|x_t|x_sp (38535168 f32 each).
//          out-section scratch: osp (bf16) -> z_sp; otb (bf16) -> z_t.
// ---------------------------------------------------------------------------

typedef __bf16 bf16x8 __attribute__((ext_vector_type(8)));
typedef float  f32x4  __attribute__((ext_vector_type(4)));

#define TOKENS   200704
#define OUT_SEC  38535168
// weight offsets (elements) inside ws bf16 region
#define W_QKV  0
#define W_PSP  110592
#define W_PT   147456
#define W_TF1  184320
#define W_TF2  331776
#define W_SF1  479232
#define W_SF2  626688
#define W_FUSE 774144
#define W_TOTAL 847872
#define OFF_BUFA 1695744ull          // bytes (= W_TOTAL*2)
#define OFF_BUFB 78766080ull         // OFF_BUFA + 200704*192*2

__device__ __forceinline__ float bf2f(unsigned short u){
  unsigned int v = ((unsigned int)u) << 16;
  return __builtin_bit_cast(float, v);
}
__device__ __forceinline__ unsigned short f2bf(float f){
  unsigned int v = __builtin_bit_cast(unsigned int, f);
  v = v + 0x7fffu + ((v >> 16) & 1u);
  return (unsigned short)(v >> 16);
}
__device__ __forceinline__ f32x4 mfma16(bf16x8 a, bf16x8 b, f32x4 c){
  return __builtin_amdgcn_mfma_f32_16x16x32_bf16(a, b, c, 0, 0, 0);
}
// async global->LDS, 16B per lane; dest must be wave-uniform-base + lane*16
__device__ __forceinline__ void gload16(const void* g, void* l){
  __builtin_amdgcn_global_load_lds(
      (const __attribute__((address_space(1))) unsigned int*)g,
      (__attribute__((address_space(3))) unsigned int*)l, 16, 0, 0);
}
// swizzled 16B-unit index inside a [R][64]-bf16 tile (linear dest layout);
// bank-optimal for ds_read_b128 (2-way max = free per m136)
__device__ __forceinline__ int swz(int row, int kq){ return (row << 3) + (kq ^ (row & 7)); }

// ---------------- weight fp32 -> bf16 cast (all 8 matrices) ----------------
__global__ __launch_bounds__(256) void wconv(
    const float* qkvw, const float* psp, const float* pt,
    const float* tf1, const float* tf2, const float* sf1, const float* sf2,
    const float* fw, unsigned short* out){
  int i = blockIdx.x * 256 + threadIdx.x;
  if (i >= W_TOTAL) return;
  const float* src; int off;
  if      (i < W_PSP ) { src = qkvw; off = W_QKV; }
  else if (i < W_PT  ) { src = psp;  off = W_PSP; }
  else if (i < W_TF1 ) { src = pt;   off = W_PT;  }
  else if (i < W_TF2 ) { src = tf1;  off = W_TF1; }
  else if (i < W_SF1 ) { src = tf2;  off = W_TF2; }
  else if (i < W_SF2 ) { src = sf1;  off = W_SF1; }
  else if (i < W_FUSE) { src = sf2;  off = W_SF2; }
  else                 { src = fw;   off = W_FUSE; }
  out[i] = f2bf(src[i - off]);
}

// ---------------- LN1 + window partition gather: x -> xn (bf16, win-major) --
__global__ __launch_bounds__(256) void ln1_gather(
    const float* __restrict__ x, const float* __restrict__ g1,
    const float* __restrict__ b1, unsigned short* __restrict__ xn){
  int wid = threadIdx.x >> 6, lane = threadIdx.x & 63;
  int g = blockIdx.x * 4 + wid;
  const float* row = x + (size_t)g * 192;
  float v0 = row[lane], v1 = row[lane + 64], v2 = row[lane + 128];
  float s = v0 + v1 + v2, ss = v0*v0 + v1*v1 + v2*v2;
  for (int m = 1; m < 64; m <<= 1){ s += __shfl_xor(s, m, 64); ss += __shfl_xor(ss, m, 64); }
  float mean = s * (1.f/192.f);
  float var  = ss * (1.f/192.f) - mean*mean;
  float rstd = rsqrtf(var + 1e-5f);
  int b = g / 25088, rem = g % 25088;
  int t = rem / 3136, l = rem % 3136;
  int h = l / 56, w_ = l % 56;
  int hh = h / 7, i2 = h % 7, ww = w_ / 7, j = w_ % 7;
  int win = (b*8 + hh)*8 + ww;
  int rw  = (win*8 + t)*49 + i2*7 + j;
  unsigned short* dst = xn + (size_t)rw * 192;
  dst[lane]       = f2bf((v0 - mean)*rstd*g1[lane]       + b1[lane]);
  dst[lane + 64]  = f2bf((v1 - mean)*rstd*g1[lane + 64]  + b1[lane + 64]);
  dst[lane + 128] = f2bf((v2 - mean)*rstd*g1[lane + 128] + b1[lane + 128]);
}

// ---------------- unified GEMM: C = A(MxK) * B(NxK)^T + bias ---------------
// BM=128, BN=192 (grid.y chunks), BK=64; 256 threads = 4 waves,
// wave w -> rows w*32..w*32+31 (2 m-frags x 12 n-frags = 24 acc).
// Staging: global_load_lds 16B/lane into linear LDS, source pre-swizzled
// (kseg ^= row&7); ds_read_b128 applies the same XOR -> conflict-free.
// MODE 0: QKV  (out bf16, cols<192 scaled by d^-0.5)
// MODE 1: FC1  (out bf16, exact-erf GELU)
// MODE 2: RESID(out f32 = acc+bias+resid; resid may alias out)
// MODE 4: RESID+LN2 (out f32 like MODE2, plus z bf16 = LN(out); grid.y==1,
//                    zout may alias A: each block reads only its own rows)
// MODE 5: FUSE (A staged from two fp32 sources [af0|af1], out f32 = acc+bias)
template<int MODE>
__global__ __launch_bounds__(256, 2) void gemm128(
    const unsigned short* __restrict__ A, int lda,
    const unsigned short* __restrict__ Bw, int K,
    const float* __restrict__ bias,
    void* __restrict__ outp, int ldo,
    const float* __restrict__ resid,
    const float* __restrict__ g2, const float* __restrict__ b2,
    unsigned short* __restrict__ zout,
    const float* __restrict__ af0, const float* __restrict__ af1){
  __shared__ unsigned short As[128 * 64];   // 16 KB
  __shared__ unsigned short Bs[192 * 64];   // 24 KB
  int tid = threadIdx.x, wid = tid >> 6, lane = tid & 63;
  int quad = lane >> 4, lm = lane & 15;
  size_t m0 = (size_t)blockIdx.x * 128;
  int n0 = blockIdx.y * 192;
  const unsigned short* Bp = Bw + (size_t)n0 * K;
  f32x4 acc[2][12];
  #pragma unroll
  for (int mt = 0; mt < 2; mt++)
    #pragma unroll
    for (int ct = 0; ct < 12; ct++) acc[mt][ct] = (f32x4){0,0,0,0};

  for (int k0 = 0; k0 < K; k0 += 64){
    if (MODE == 5){
      // manual f32->bf16 staging (can write swizzled directly)
      #pragma unroll
      for (int i = 0; i < 4; i++){
        int flat = tid + i*256, row = flat >> 3, seg = flat & 7;
        int kg = k0 + ((seg ^ (row & 7)) << 3);
        const float* sp = (kg < 192) ? af0 : af1;
        int kk = (kg < 192) ? kg : kg - 192;
        const float* s8 = sp + (m0 + row) * 192 + kk;
        float4 p0 = *(const float4*)(s8);
        float4 p1 = *(const float4*)(s8 + 4);
        uint4 val;
        val.x = f2bf(p0.x) | ((unsigned int)f2bf(p0.y) << 16);
        val.y = f2bf(p0.z) | ((unsigned int)f2bf(p0.w) << 16);
        val.z = f2bf(p1.x) | ((unsigned int)f2bf(p1.y) << 16);
        val.w = f2bf(p1.z) | ((unsigned int)f2bf(p1.w) << 16);
        *(uint4*)&As[flat * 8] = val;
      }
    } else {
      #pragma unroll
      for (int i = 0; i < 4; i++){
        int flat = tid + i*256, row = flat >> 3, seg = flat & 7;
        gload16(&A[(m0 + row) * (size_t)lda + k0 + ((seg ^ (row & 7)) << 3)],
                &As[flat * 8]);
      }
    }
    #pragma unroll
    for (int i = 0; i < 6; i++){
      int flat = tid + i*256, row = flat >> 3, seg = flat & 7;
      gload16(&Bp[(size_t)row * K + k0 + ((seg ^ (row & 7)) << 3)],
              &Bs[flat * 8]);
    }
    __syncthreads();   // drains vmcnt (gload_lds) + lgkmcnt
    #pragma unroll
    for (int ks = 0; ks < 2; ks++){
      int kx = ks * 4 + quad;
      bf16x8 a0 = *(const bf16x8*)&As[swz(wid*32 + lm,      kx) * 8];
      bf16x8 a1 = *(const bf16x8*)&As[swz(wid*32 + 16 + lm, kx) * 8];
      #pragma unroll
      for (int ct = 0; ct < 12; ct++){
        bf16x8 bfr = *(const bf16x8*)&Bs[swz(ct*16 + lm, kx) * 8];
        acc[0][ct] = mfma16(a0, bfr, acc[0][ct]);
        acc[1][ct] = mfma16(a1, bfr, acc[1][ct]);
      }
    }
    __syncthreads();
  }

  // ---- epilogue; C layout: col = n0+ct*16+lm, row = wid*32+mt*16+quad*4+r
  if (MODE == 0 || MODE == 1){
    unsigned short* out = (unsigned short*)outp;
    float bv[12];
    #pragma unroll
    for (int ct = 0; ct < 12; ct++) bv[ct] = bias[n0 + ct*16 + lm];
    #pragma unroll
    for (int mt = 0; mt < 2; mt++)
      #pragma unroll
      for (int ct = 0; ct < 12; ct++){
        int n = n0 + ct*16 + lm;
        #pragma unroll
        for (int r = 0; r < 4; r++){
          size_t m = m0 + wid*32 + mt*16 + quad*4 + r;
          float v = acc[mt][ct][r] + bv[ct];
          if (MODE == 0){
            if (n < 192) v *= 0.17677669529663687f;  // q * d^-0.5 folded in
            out[m * ldo + n] = f2bf(v);
          } else {
            float ge = 0.5f * v * (1.f + erff(v * 0.70710678118654752f));
            out[m * ldo + n] = f2bf(ge);
          }
        }
      }
  } else if (MODE == 5){
    float* out = (float*)outp;
    float bv[12];
    #pragma unroll
    for (int ct = 0; ct < 12; ct++) bv[ct] = bias[ct*16 + lm];
    #pragma unroll
    for (int mt = 0; mt < 2; mt++)
      #pragma unroll
      for (int r = 0; r < 4; r++){
        size_t m = m0 + wid*32 + mt*16 + quad*4 + r;
        float* orow = out + m * 192;
        #pragma unroll
        for (int ct = 0; ct < 12; ct++) orow[ct*16 + lm] = acc[mt][ct][r] + bv[ct];
      }
  } else {  // MODE 2 / 4 (full row per block: grid.y == 1, ldo == 192)
    float* out = (float*)outp;
    float bv[12];
    #pragma unroll
    for (int ct = 0; ct < 12; ct++) bv[ct] = bias[ct*16 + lm];
    float g2v[12], b2v[12];
    if (MODE == 4){
      #pragma unroll
      for (int ct = 0; ct < 12; ct++){ g2v[ct] = g2[ct*16 + lm]; b2v[ct] = b2[ct*16 + lm]; }
    }
    #pragma unroll
    for (int mt = 0; mt < 2; mt++)
      #pragma unroll
      for (int r = 0; r < 4; r++){
        size_t m = m0 + wid*32 + mt*16 + quad*4 + r;
        const float* rrow = resid + m * 192;
        float vv[12]; float s = 0.f, ss = 0.f;
        #pragma unroll
        for (int ct = 0; ct < 12; ct++){
          float v = acc[mt][ct][r] + bv[ct] + rrow[ct*16 + lm];
          vv[ct] = v; s += v; ss += v * v;
        }
        float* orow = out + m * 192;
        if (MODE == 4){
          // row lives in the 16 lanes of this quad (xor masks < 16)
          #pragma unroll
          for (int mm = 1; mm < 16; mm <<= 1){
            s += __shfl_xor(s, mm, 64); ss += __shfl_xor(ss, mm, 64);
          }
          float mean = s * (1.f/192.f);
          float var  = ss * (1.f/192.f) - mean*mean;
          float rstd = rsqrtf(var + 1e-5f);
          unsigned short* zrow = zout + m * 192;
          #pragma unroll
          for (int ct = 0; ct < 12; ct++){
            float v = vv[ct];
            orow[ct*16 + lm] = v;
            zrow[ct*16 + lm] = f2bf((v - mean) * rstd * g2v[ct] + b2v[ct]);
          }
        } else {
          #pragma unroll
          for (int ct = 0; ct < 12; ct++) orow[ct*16 + lm] = vv[ct];
        }
      }
  }
}

// ---------------- spatial window attention (S=49 pad 64, per (win,t)) ------
__global__ __launch_bounds__(256) void attn_sp(
    const unsigned short* __restrict__ qkv, unsigned short* __restrict__ osp){
  __shared__ unsigned short qh[64 * 40];
  __shared__ unsigned short kh[64 * 40];
  __shared__ unsigned short vT[32 * 72];   // [d][t]
  __shared__ unsigned short pl[64 * 72];   // [row][k]
  int tid = threadIdx.x, wid = tid >> 6, lane = tid & 63;
  int quad = lane >> 4, lm = lane & 15;
  int inst = blockIdx.x;                    // win*8 + t
  int win = inst >> 3, t = inst & 7;
  size_t rowbase = (size_t)inst * 49;
  int b = win >> 6, hh = (win >> 3) & 7, ww = win & 7;
  int lbase = (b * 8 + t) * 3136;

  for (int h = 0; h < 6; h++){
    { // stage q (scaled already) and k, zero pad rows 49..63
      int row = tid >> 2, seg = tid & 3;
      uint4 z4; z4.x = z4.y = z4.z = z4.w = 0u;
      uint4 vq = z4, vk = z4;
      if (row < 49){
        vq = *(const uint4*)&qkv[(rowbase + row) * 576 + h * 32 + seg * 8];
        vk = *(const uint4*)&qkv[(rowbase + row) * 576 + 192 + h * 32 + seg * 8];
      }
      *(uint4*)&qh[row * 40 + seg * 8] = vq;
      *(uint4*)&kh[row * 40 + seg * 8] = vk;
    }
    // stage v transposed: vT[d][t]
    for (int c = tid; c < 2048; c += 256){
      int row = c >> 5, d = c & 31;
      unsigned short val = 0;
      if (row < 49) val = qkv[(rowbase + row) * 576 + 384 + h * 32 + d];
      vT[d * 72 + row] = val;
    }
    __syncthreads();
    // S = q k^T  (wave w -> rows w*16..+15), K=32 = one MFMA step
    bf16x8 aq = *(const bf16x8*)&qh[(wid * 16 + lm) * 40 + quad * 8];
    f32x4 s[4];
    for (int ct = 0; ct < 4; ct++){
      bf16x8 bk = *(const bf16x8*)&kh[(ct * 16 + lm) * 40 + quad * 8];
      f32x4 z = (f32x4){0,0,0,0};
      s[ct] = mfma16(aq, bk, z);
    }
    // mask cols >= 49, row softmax (row lives in one quad: 16 lanes x 4 tiles)
    for (int r = 0; r < 4; r++){
      float mx = -1e30f;
      for (int ct = 0; ct < 4; ct++){
        int col = ct * 16 + lm;
        if (col >= 49) s[ct][r] = -1e30f;
        mx = fmaxf(mx, s[ct][r]);
      }
      for (int m = 1; m < 16; m <<= 1) mx = fmaxf(mx, __shfl_xor(mx, m, 64));
      float sm = 0.f;
      for (int ct = 0; ct < 4; ct++){
        float e = __expf(s[ct][r] - mx);
        s[ct][r] = e; sm += e;
      }
      for (int m = 1; m < 16; m <<= 1) sm += __shfl_xor(sm, m, 64);
      float inv = 1.f / sm;
      for (int ct = 0; ct < 4; ct++) s[ct][r] *= inv;
    }
    // P -> LDS (C layout -> A layout round trip)
    for (int ct = 0; ct < 4; ct++){
      int col = ct * 16 + lm;
      for (int r = 0; r < 4; r++){
        int row = wid * 16 + quad * 4 + r;
        pl[row * 72 + col] = f2bf(s[ct][r]);
      }
    }
    __syncthreads();
    // O = P @ V : M=16/wave, N=32, K=64
    f32x4 o[2] = {(f32x4){0,0,0,0}, (f32x4){0,0,0,0}};
    for (int k0 = 0; k0 < 64; k0 += 32){
      bf16x8 ap = *(const bf16x8*)&pl[(wid * 16 + lm) * 72 + k0 + quad * 8];
      for (int ct = 0; ct < 2; ct++){
        bf16x8 bv = *(const bf16x8*)&vT[(ct * 16 + lm) * 72 + k0 + quad * 8];
        o[ct] = mfma16(ap, bv, o[ct]);
      }
    }
    // write O to flat-token layout (fold window-reverse)
    for (int ct = 0; ct < 2; ct++){
      for (int r = 0; r < 4; r++){
        int n = wid * 16 + quad * 4 + r;
        if (n < 49){
          int i2 = n / 7, j = n % 7;
          size_t g = (size_t)lbase + (hh * 7 + i2) * 56 + ww * 7 + j;
          osp[g * 192 + h * 32 + ct * 16 + lm] = f2bf(o[ct][r]);
        }
      }
    }
    __syncthreads();
  }
}

// ---------------- temporal attention (S=T=8, per (win,n), VALU) ------------
__global__ __launch_bounds__(256) void attn_t(
    const unsigned short* __restrict__ qkv, unsigned short* __restrict__ ot){
  __shared__ unsigned short lds[4][8][576];
  int wid = threadIdx.x >> 6, lane = threadIdx.x & 63;
  int inst = blockIdx.x * 4 + wid;     // 0..25087
  int win = inst / 49, n = inst % 49;
  for (int c = lane; c < 576; c += 64){
    int row = c / 72, seg = c % 72;
    *(uint4*)&lds[wid][row][seg * 8] =
        *(const uint4*)&qkv[((size_t)((win * 8 + row) * 49 + n)) * 576 + seg * 8];
  }
  __syncthreads();
  int tq = lane >> 3, tk = lane & 7;
  int b = win >> 6, hh = (win >> 3) & 7, ww = win & 7;
  int i2 = n / 7, j = n % 7;
  int l = (hh * 7 + i2) * 56 + ww * 7 + j;
  size_t gtok = (size_t)(b * 8 + tq) * 3136 + l;
  for (int h = 0; h < 6; h++){
    const unsigned short* qr = &lds[wid][tq][h * 32];
    const unsigned short* kr = &lds[wid][tk][192 + h * 32];
    float s = 0.f;
    for (int d = 0; d < 32; d++) s += bf2f(qr[d]) * bf2f(kr[d]);
    float mx = s;
    for (int m = 1; m < 8; m <<= 1) mx = fmaxf(mx, __shfl_xor(mx, m, 64));
    float p = __expf(s - mx);
    float sum = p;
    for (int m = 1; m < 8; m <<= 1) sum += __shfl_xor(sum, m, 64);
    p /= sum;
    // PV: lane -> (tq, dgrp=tk): o[tq][tk*4..+3]
    float o0 = 0, o1 = 0, o2 = 0, o3 = 0;
    for (int k2 = 0; k2 < 8; k2++){
      float pk = __shfl(p, (lane & 56) + k2, 64);
      const unsigned short* vr = &lds[wid][k2][384 + h * 32 + tk * 4];
      o0 += pk * bf2f(vr[0]); o1 += pk * bf2f(vr[1]);
      o2 += pk * bf2f(vr[2]); o3 += pk * bf2f(vr[3]);
    }
    unsigned short* dst = &ot[gtok * 192 + h * 32 + tk * 4];
    dst[0] = f2bf(o0); dst[1] = f2bf(o1); dst[2] = f2bf(o2); dst[3] = f2bf(o3);
  }
}

// ---------------------------------------------------------------------------
extern "C" void kernel_launch(void* const* d_in, const int* in_sizes, int n_in,
                              void* d_out, int out_size, void* d_ws, size_t ws_size,
                              hipStream_t stream){
  const float* x     = (const float*)d_in[0];
  const float* n1g   = (const float*)d_in[2];
  const float* n1b   = (const float*)d_in[3];
  const float* qkvw  = (const float*)d_in[4];
  const float* qkvb  = (const float*)d_in[5];
  const float* pspw  = (const float*)d_in[6];
  const float* pspb  = (const float*)d_in[7];
  const float* ptw   = (const float*)d_in[8];
  const float* ptb   = (const float*)d_in[9];
  const float* n2g   = (const float*)d_in[10];
  const float* n2b   = (const float*)d_in[11];
  const float* tf1w  = (const float*)d_in[12];
  const float* tf1b  = (const float*)d_in[13];
  const float* tf2w  = (const float*)d_in[14];
  const float* tf2b  = (const float*)d_in[15];
  const float* sf1w  = (const float*)d_in[16];
  const float* sf1b  = (const float*)d_in[17];
  const float* sf2w  = (const float*)d_in[18];
  const float* sf2b  = (const float*)d_in[19];
  const float* fw    = (const float*)d_in[20];
  const float* fb    = (const float*)d_in[21];

  unsigned short* wbf = (unsigned short*)d_ws;
  unsigned short* xn  = (unsigned short*)((char*)d_ws + OFF_BUFA);
  unsigned short* qkv = (unsigned short*)((char*)d_ws + OFF_BUFB);
  unsigned short* hbuf = xn;  // spans bufA+bufB = 308.28MB contiguous

  float* out0 = (float*)d_out;
  float* xt   = out0 + OUT_SEC;
  float* xsp  = out0 + 2 * (size_t)OUT_SEC;
  unsigned short* osp = (unsigned short*)d_out;            // scratch in out sec
  unsigned short* otb = (unsigned short*)d_out + OUT_SEC;  // scratch in out sec
  // z_t aliases otb, z_sp aliases osp (per-block rows consumed before write)

  wconv<<<3312, 256, 0, stream>>>(qkvw, pspw, ptw, tf1w, tf2w, sf1w, sf2w, fw, wbf);
  ln1_gather<<<50176, 256, 0, stream>>>(x, n1g, n1b, xn);
  // QKV: (200704x192) @ (576x192)^T -> qkv bf16 ld 576
  gemm128<0><<<dim3(1568, 3), 256, 0, stream>>>(xn, 192, wbf + W_QKV, 192, qkvb,
      qkv, 576, nullptr, nullptr, nullptr, nullptr, nullptr, nullptr);
  attn_sp<<<4096, 256, 0, stream>>>(qkv, osp);
  attn_t<<<6272, 256, 0, stream>>>(qkv, otb);
  // temporal branch: proj_t + resid + LN2 fused (xt f32, z_t bf16 -> otb)
  gemm128<4><<<dim3(1568, 1), 256, 0, stream>>>(otb, 192, wbf + W_PT, 192, ptb,
      xt, 192, x, n2g, n2b, otb, nullptr, nullptr);
  gemm128<1><<<dim3(1568, 4), 256, 0, stream>>>(otb, 192, wbf + W_TF1, 192, tf1b,
      hbuf, 768, nullptr, nullptr, nullptr, nullptr, nullptr, nullptr);
  gemm128<2><<<dim3(1568, 1), 256, 0, stream>>>(hbuf, 768, wbf + W_TF2, 768, tf2b,
      xt, 192, xt, nullptr, nullptr, nullptr, nullptr, nullptr);
  // spatial branch: proj_sp + resid + LN2 fused (xsp f32, z_sp bf16 -> osp)
  gemm128<4><<<dim3(1568, 1), 256, 0, stream>>>(osp, 192, wbf + W_PSP, 192, pspb,
      xsp, 192, x, n2g, n2b, osp, nullptr, nullptr);
  gemm128<1><<<dim3(1568, 4), 256, 0, stream>>>(osp, 192, wbf + W_SF1, 192, sf1b,
      hbuf, 768, nullptr, nullptr, nullptr, nullptr, nullptr, nullptr);
  gemm128<2><<<dim3(1568, 1), 256, 0, stream>>>(hbuf, 768, wbf + W_SF2, 768, sf2b,
      xsp, 192, xsp, nullptr, nullptr, nullptr, nullptr, nullptr);
  // fuse: out = [x_t | x_sp] @ fuse_w^T + fuse_b
  gemm128<5><<<dim3(1568, 1), 256, 0, stream>>>(nullptr, 0, wbf + W_FUSE, 384, fb,
      out0, 192, nullptr, nullptr, nullptr, nullptr, xt, xsp);
}